// Round 15
// baseline (457.855 us; speedup 1.0000x reference)
//
#include <hip/hip_runtime.h>

// T=512, B=512, K=8, V=5, H=30, NL=4, NLAB=3
#define TT 512
#define BB 512
#define KK 8
#define HH 30
#define GG 120   // 4*H
#define NLAYER 4

typedef _Float16 half2v __attribute__((ext_vector_type(2)));

__device__ __forceinline__ float rcp_f(float x) { return __builtin_amdgcn_rcpf(x); }
__device__ __forceinline__ float rdlane_f(float v, int l) {
    return __int_as_float(__builtin_amdgcn_readlane(__float_as_int(v), l));
}
__device__ __forceinline__ unsigned int rdlane_u(unsigned int v, int l) {
    return (unsigned int)__builtin_amdgcn_readlane((int)v, l);
}
__device__ __forceinline__ half2v as_h2(unsigned int u) {
    union { unsigned int u; half2v h; } c; c.u = u; return c.h;
}
// packed f32 FMA, broadcast operand in SGPR pair (attention epilogue)
__device__ __forceinline__ float2 pk_fma_s(float2 a, float2 bs, float2 c) {
    float2 d;
    asm("v_pk_fma_f32 %0, %1, %2, %3" : "=v"(d) : "v"(a), "s"(bs), "v"(c));
    return d;
}
// value from lane^32 partner (valid for lanes < 32; lanes >= 32 get lo value)
__device__ __forceinline__ float swap32_hi(float x) {
    float a = x, b = x;
    asm("v_permlane32_swap_b32 %0, %1" : "+v"(a), "+v"(b));
    return b;   // lanes<32: x[lane+32]
}

// R15 = R14 (371.5 us: R8 engine + s_setprio phase hinting, +6.3% matched
// prediction) + SOFTWARE-PIPELINED x-side: the x MACs of step t+1 (30
// independent v_dot2 + 4 uniform ds_read_b128; group's x already published)
// are computed in the prio-0 region alongside step t's ~300-cyc serial
// activation chain. Per-wave ILP fill complements R14's cross-wave priority
// fill: the ~25% window where BOTH waves sit in their chains now has
// runnable work. Op order per accumulator unchanged -> bit-identical.
__global__ __launch_bounds__(256) __attribute__((amdgpu_waves_per_eu(2, 2)))
void rnn_fused(
    const int*   __restrict__ xin,  const float* __restrict__ wxin,
    const float* __restrict__ embed,
    const float* __restrict__ Wih,  const float* __restrict__ Whh,
    const float* __restrict__ bih,  const float* __restrict__ bhh,
    const float* __restrict__ W1,   const float* __restrict__ b1,
    const float* __restrict__ W2,   const float* __restrict__ b2,
    const float* __restrict__ fcW,  const float* __restrict__ fcb,
    float* __restrict__ out)
{
    __shared__ alignas(16) float hstore[TT * HH];              // layer-3 h trace (f32)
    __shared__ alignas(16) unsigned int seqring16[2][16][16];  // pooled-embed, f16 pairs
    __shared__ alignas(16) int   ringx[4][16][KK];             // x stream (wave-0 private)
    __shared__ alignas(16) float ringw[4][16][KK];
    __shared__ alignas(16) unsigned int hring16[3][16][16];    // layer->layer h, f16 pairs
    __shared__ alignas(16) float re_s[5 * HH];                 // relu(embed)
    __shared__ alignas(16) float energy_s[TT];
    __shared__ float red_s[16];
    __shared__ float part_s[8][HH];
    __shared__ float pooled_s[HH];
    __shared__ float logits_s[3];
    __shared__ int   sync_s[8];                                // [0..3]=prog, [4..7]=cons

    const int tid  = threadIdx.x;
    const int wv   = tid >> 6;
    const int lane = tid & 63;
    const int b    = blockIdx.x;
    volatile int* vs = sync_s;

    // ---- preamble ----
    if (tid < 8) sync_s[tid] = 0;
    if (tid < 5 * HH) re_s[tid] = fmaxf(embed[tid], 0.0f);

    int4 hx = {0,0,0,0}; float4 hw = {0,0,0,0};          // held x/w (wave0, lanes<32)
    if (wv == 0 && lane < 32) {
        const int r = lane >> 1, hf = lane & 1;
        #pragma unroll
        for (int cc = 0; cc < 2; ++cc) {                 // chunks 0,1 -> LDS
            long off = ((long)(16 * cc + r) * BB + b) * KK + hf * 4;
            *(int4*)(&ringx[cc][r][hf * 4])   = *(const int4*)(xin  + off);
            *(float4*)(&ringw[cc][r][hf * 4]) = *(const float4*)(wxin + off);
        }
        long off2 = ((long)(32 + r) * BB + b) * KK + hf * 4;  // chunk 2 -> regs
        hx = *(const int4*)(xin  + off2);
        hw = *(const float4*)(wxin + off2);
    }

    // ---- per-lane LSTM weights, XOR-32 gate layout, packed f16 pairs ----
    // half0 (lanes 0..31):  rowA = i-row q,    rowB = g-row q+60
    // half1 (lanes 32..63): rowA = f-row q+30, rowB = o-row q+90
    const int half = lane >> 5;
    const int q31  = lane & 31;
    const int qq   = (q31 < HH) ? q31 : (HH - 1);        // clamp dead lanes
    const int rA   = qq + half * HH;                     // 0..59
    const int rB   = rA + 60;                            // 60..119
    half2v wihA_h[15], wihB_h[15], whhA_h[15], whhB_h[15];
    {
        const float* WihL = Wih + wv * GG * HH;
        const float* WhhL = Whh + wv * GG * HH;
        #pragma unroll
        for (int kk = 0; kk < 15; ++kk) {
            float2 a0 = *(const float2*)(WihL + rA * HH + 2 * kk);
            float2 a1 = *(const float2*)(WihL + rB * HH + 2 * kk);
            float2 a2 = *(const float2*)(WhhL + rA * HH + 2 * kk);
            float2 a3 = *(const float2*)(WhhL + rB * HH + 2 * kk);
            wihA_h[kk][0] = (_Float16)a0.x; wihA_h[kk][1] = (_Float16)a0.y;
            wihB_h[kk][0] = (_Float16)a1.x; wihB_h[kk][1] = (_Float16)a1.y;
            whhA_h[kk][0] = (_Float16)a2.x; whhA_h[kk][1] = (_Float16)a2.y;
            whhB_h[kk][0] = (_Float16)a3.x; whhB_h[kk][1] = (_Float16)a3.y;
        }
    }
    const float biasA = bih[wv * GG + rA] + bhh[wv * GG + rA];
    const float biasB = bih[wv * GG + rB] + bhh[wv * GG + rB];
    const float mBneg = (lane < 32) ? -2.0f : -1.0f;     // half0: tanh via 2*sig(2x)-1
    const float aB    = (lane < 32) ?  2.0f :  1.0f;
    const float dB    = (lane < 32) ? -1.0f :  0.0f;

    __syncthreads();   // preamble visible (ringx/re_s/sync init)

    float c_val = 0.0f;
    unsigned int hpk = 0;   // own h as packed f16 pair: even lane 2k holds (h2k, h2k+1)

    // x-side MACs for step t (reads ring, 30 fdot2) -- used for the
    // software pipeline prologue and per-step lookahead
    auto x_macs = [&](int t, float& axA, float& axB) {
        const unsigned int* xsrc = (wv == 0) ? &seqring16[(t >> 4) & 1][t & 15][0]
                                             : &hring16[wv - 1][t & 15][0];
        uint4 q0 = ((const uint4*)xsrc)[0];
        uint4 q1 = ((const uint4*)xsrc)[1];
        uint4 q2 = ((const uint4*)xsrc)[2];
        uint4 q3 = ((const uint4*)xsrc)[3];
        const unsigned int xu[16] = {q0.x,q0.y,q0.z,q0.w, q1.x,q1.y,q1.z,q1.w,
                                     q2.x,q2.y,q2.z,q2.w, q3.x,q3.y,q3.z,q3.w};
        axA = 0.f; axB = 0.f;
        #pragma unroll
        for (int k = 0; k < 15; ++k) {
            const half2v xp = as_h2(xu[k]);
            axA = __builtin_amdgcn_fdot2(wihA_h[k], xp, axA, false);
            axB = __builtin_amdgcn_fdot2(wihB_h[k], xp, axB, false);
        }
    };

    // ---- elastic pipelined recurrence: 64 groups of 8 steps ----
    for (int T0 = 0; T0 < TT; T0 += 8) {
        if (wv == 0) {
            if ((T0 & 15) == 0) {                        // chunk boundary (private)
                const int c = T0 >> 4;
                if (lane < 32) {
                    const int r = lane >> 1, hf = lane & 1;
                    if (c <= 29) {                       // commit chunk c+2
                        const int sl = (c + 2) & 3;
                        *(int4*)(&ringx[sl][r][hf * 4])   = hx;
                        *(float4*)(&ringw[sl][r][hf * 4]) = hw;
                    }
                    if (c <= 28) {                       // load chunk c+3
                        long off = ((long)(16 * (c + 3) + r) * BB + b) * KK + hf * 4;
                        hx = *(const int4*)(xin  + off);
                        hw = *(const float4*)(wxin + off);
                    }
                }
                const int sl = c & 3, par = c & 1;       // gather pooled chunk c
                #pragma unroll
                for (int rr = 0; rr < 8; ++rr) {
                    const int o = lane + rr * 64;
                    if (o < 480) {
                        const int tr = o / HH, j = o - tr * HH;
                        int4   xa = *(const int4*)(&ringx[sl][tr][0]);
                        int4   xb = *(const int4*)(&ringx[sl][tr][4]);
                        float4 wa = *(const float4*)(&ringw[sl][tr][0]);
                        float4 wb = *(const float4*)(&ringw[sl][tr][4]);
                        float acc = re_s[xa.x * HH + j] * wa.x;
                        acc = fmaf(re_s[xa.y * HH + j], wa.y, acc);
                        acc = fmaf(re_s[xa.z * HH + j], wa.z, acc);
                        acc = fmaf(re_s[xa.w * HH + j], wa.w, acc);
                        acc = fmaf(re_s[xb.x * HH + j], wb.x, acc);
                        acc = fmaf(re_s[xb.y * HH + j], wb.y, acc);
                        acc = fmaf(re_s[xb.z * HH + j], wb.z, acc);
                        acc = fmaf(re_s[xb.w * HH + j], wb.w, acc);
                        // store pooled value as f16 (u16 element j of the pair row)
                        ((_Float16*)&seqring16[par][tr][0])[j] = (_Float16)(acc * 0.125f);
                    }
                }
                __threadfence_block();                   // gather visible to own reads
            }
        } else {
            while (vs[wv - 1] < T0 + 8) __builtin_amdgcn_s_sleep(1);   // x ready
        }
        if (wv < NLAYER - 1) {
            while (vs[4 + wv + 1] < T0 - 8) __builtin_amdgcn_s_sleep(1); // ring free
        }
        __threadfence_block();                           // order spins vs ring reads

        // ---- software-pipelined 8-step group ----
        float axA, axB;
        x_macs(T0, axA, axB);                            // prologue: step 0's x-side
        #pragma unroll 1
        for (int tt = 0; tt < 8; ++tt) {                 // NOT unrolled: ~1KB body
            const int t = T0 + tt;
            // ---- h-side MAC burst: high ILP, elevated priority ----
            __builtin_amdgcn_s_setprio(1);
            float ahA = 0.f, ahB = 0.f, ahA2 = 0.f, ahB2 = 0.f;
            #pragma unroll
            for (int k = 0; k < 8; ++k) {
                const half2v hp = as_h2(rdlane_u(hpk, 2 * k));
                ahA = __builtin_amdgcn_fdot2(whhA_h[k], hp, ahA, false);
                ahB = __builtin_amdgcn_fdot2(whhB_h[k], hp, ahB, false);
            }
            #pragma unroll
            for (int k = 8; k < 15; ++k) {
                const half2v hp = as_h2(rdlane_u(hpk, 2 * k));
                ahA2 = __builtin_amdgcn_fdot2(whhA_h[k], hp, ahA2, false);
                ahB2 = __builtin_amdgcn_fdot2(whhB_h[k], hp, ahB2, false);
            }
            // ---- serial chain at low priority, with NEXT step's x-side
            // MACs as per-wave ILP fill (independent of the chain) ----
            __builtin_amdgcn_s_setprio(0);
            float axA_n = 0.f, axB_n = 0.f;
            if (tt < 7) x_macs(t + 1, axA_n, axB_n);     // fills chain stalls
            const float gA = (axA + ahA) + (ahA2 + biasA);   // i | f
            const float gB = (axB + ahB) + (ahB2 + biasB);   // g | o
            const float actA = rcp_f(1.0f + __expf(-gA));    // sigmoid (both halves)
            const float sB   = rcp_f(1.0f + __expf(gB * mBneg));
            const float actB = fmaf(aB, sB, dB);             // tanh | sigmoid
            const float fI = swap32_hi(actA);                // f from lane+32
            const float oI = swap32_hi(actB);                // o from lane+32
            c_val = fmaf(fI, c_val, actA * actB);            // valid on lanes 0..29
            const float tC = fmaf(2.0f, rcp_f(1.0f + __expf(-2.0f * c_val)), -1.0f);
            const float hv = oI * tC;
            // pack f16 pair: own (lo) | quad-perm partner (hi) -- even lanes valid
            union { _Float16 f[2]; unsigned int u; } cv; cv.u = 0;
            cv.f[0] = (_Float16)hv;
            const unsigned int hu  = cv.u;
            const unsigned int hup = (unsigned int)__builtin_amdgcn_mov_dpp(
                                         (int)hu, 0xB1, 0xF, 0xF, true); // [1,0,3,2]
            hpk = hu | (hup << 16);
            if (lane < HH) {
                if (wv == NLAYER - 1) hstore[t * HH + lane] = hv;          // f32 trace
                else if (!(lane & 1)) hring16[wv][t & 15][lane >> 1] = hpk; // f16 pairs
            }
            axA = axA_n; axB = axB_n;                    // advance pipeline
        }

        __threadfence_block();                           // drain h writes
        if (lane == 0) {
            if (wv < NLAYER - 1) vs[wv]     = T0 + 8;    // producer progress
            if (wv > 0)          vs[4 + wv] = T0 + 8;    // consumer progress
        }
    }

    __syncthreads();   // hstore complete

    // ---- attention, t-per-lane: e_t = relu(h_t @ W1 + b1) @ W2 + b2 ----
    {
        // launder pointers so these loop-invariant loads CANNOT be hoisted
        // above the recurrence
        const float* W1p = W1;
        const float* b1p = b1;
        const float* W2p = W2;
        asm volatile("" : "+v"(W1p), "+v"(b1p), "+v"(W2p));

        float w1cx[15], w1cy[15];                        // W1 column `lane`
        #pragma unroll
        for (int k = 0; k < 15; ++k) {
            w1cx[k] = W1p[(2 * k) * 64 + lane];
            w1cy[k] = W1p[(2 * k + 1) * 64 + lane];
        }
        const float b1v = b1p[lane];
        const float w2v = W2p[lane];
        const float b2v = b2[0];
        #pragma unroll
        for (int pass = 0; pass < 2; ++pass) {
            const int t = wv * 128 + pass * 64 + lane;   // each lane owns one t
            float2 h2[15];
            #pragma unroll
            for (int k = 0; k < 15; ++k)
                h2[k] = *(const float2*)(hstore + t * HH + 2 * k);
            float e = b2v;
            for (int u = 0; u < 64; ++u) {               // W1 broadcast via readlane
                float2 acc = {0.f, 0.f};
                #pragma unroll
                for (int k = 0; k < 15; ++k) {
                    float2 wp;
                    wp.x = rdlane_f(w1cx[k], u);
                    wp.y = rdlane_f(w1cy[k], u);
                    acc = pk_fma_s(h2[k], wp, acc);
                }
                const float su = acc.x + acc.y + rdlane_f(b1v, u);
                e = fmaf(fmaxf(su, 0.0f), rdlane_f(w2v, u), e);
            }
            energy_s[t] = e;
        }
    }
    __syncthreads();

    // ---- softmax over T ----
    float mx = -3.0e38f;
    for (int i = tid; i < TT; i += 256) mx = fmaxf(mx, energy_s[i]);
    #pragma unroll
    for (int m = 1; m < 64; m <<= 1) mx = fmaxf(mx, __shfl_xor(mx, m, 64));
    if (lane == 0) red_s[wv] = mx;
    __syncthreads();
    mx = fmaxf(fmaxf(red_s[0], red_s[1]), fmaxf(red_s[2], red_s[3]));
    float ssum = 0.0f;
    for (int i = tid; i < TT; i += 256) {
        float ev = __expf(energy_s[i] - mx);
        energy_s[i] = ev;
        ssum += ev;
    }
    #pragma unroll
    for (int m = 1; m < 64; m <<= 1) ssum += __shfl_xor(ssum, m, 64);
    if (lane == 0) red_s[8 + wv] = ssum;
    __syncthreads();
    const float invS = rcp_f(red_s[8] + red_s[9] + red_s[10] + red_s[11]);

    // ---- pooled_j = sum_t softmax_t * h[t][j] ----
    {
        const int g = tid >> 5, jj = tid & 31;
        if (jj < HH) {
            float part = 0.0f;
            for (int t = g; t < TT; t += 8)
                part = fmaf(energy_s[t] * invS, hstore[t * HH + jj], part);
            part_s[g][jj] = part;
        }
    }
    __syncthreads();
    if (tid < HH) {
        float pv = 0.0f;
        #pragma unroll
        for (int q = 0; q < 8; ++q) pv += part_s[q][tid];
        pooled_s[tid] = pv;
    }
    __syncthreads();

    // ---- FC (30->3) + softmax ----
    if (tid < 3) {
        float acc = fcb[tid];
        #pragma unroll
        for (int k = 0; k < HH; ++k) acc = fmaf(pooled_s[k], fcW[k * 3 + tid], acc);
        logits_s[tid] = acc;
    }
    __syncthreads();
    if (tid == 0) {
        float l0 = logits_s[0], l1 = logits_s[1], l2 = logits_s[2];
        float m3 = fmaxf(l0, fmaxf(l1, l2));
        float e0 = __expf(l0 - m3), e1 = __expf(l1 - m3), e2 = __expf(l2 - m3);
        float inv = rcp_f(e0 + e1 + e2);
        out[b * 3 + 0] = e0 * inv; out[b * 3 + 1] = e1 * inv; out[b * 3 + 2] = e2 * inv;
    }
}

extern "C" void kernel_launch(void* const* d_in, const int* in_sizes, int n_in,
                              void* d_out, int out_size, void* d_ws, size_t ws_size,
                              hipStream_t stream)
{
    (void)in_sizes; (void)n_in; (void)d_ws; (void)ws_size; (void)out_size;
    rnn_fused<<<BB, 256, 0, stream>>>(
        (const int*)  d_in[0],  (const float*)d_in[1],  (const float*)d_in[2],
        (const float*)d_in[3],  (const float*)d_in[4],  (const float*)d_in[5],
        (const float*)d_in[6],  (const float*)d_in[7],  (const float*)d_in[8],
        (const float*)d_in[9],  (const float*)d_in[10], (const float*)d_in[11],
        (const float*)d_in[12], (float*)d_out);
}

// Round 16
// 419.378 us; speedup vs baseline: 1.0917x; 1.0917x over previous
//
#include <hip/hip_runtime.h>

// T=512, B=512, K=8, V=5, H=30, NL=4, NLAB=3
#define TT 512
#define BB 512
#define KK 8
#define HH 30
#define GG 120   // 4*H
#define NLAYER 4

typedef _Float16 half2v __attribute__((ext_vector_type(2)));

__device__ __forceinline__ float rcp_f(float x) { return __builtin_amdgcn_rcpf(x); }
__device__ __forceinline__ float rdlane_f(float v, int l) {
    return __int_as_float(__builtin_amdgcn_readlane(__float_as_int(v), l));
}
__device__ __forceinline__ unsigned int rdlane_u(unsigned int v, int l) {
    return (unsigned int)__builtin_amdgcn_readlane((int)v, l);
}
__device__ __forceinline__ half2v as_h2(unsigned int u) {
    union { unsigned int u; half2v h; } c; c.u = u; return c.h;
}
// packed f32 FMA, broadcast operand in SGPR pair (attention epilogue)
__device__ __forceinline__ float2 pk_fma_s(float2 a, float2 bs, float2 c) {
    float2 d;
    asm("v_pk_fma_f32 %0, %1, %2, %3" : "=v"(d) : "v"(a), "s"(bs), "v"(c));
    return d;
}
// value from lane^32 partner (valid for lanes < 32; lanes >= 32 get lo value)
__device__ __forceinline__ float swap32_hi(float x) {
    float a = x, b = x;
    asm("v_permlane32_swap_b32 %0, %1" : "+v"(a), "+v"(b));
    return b;   // lanes<32: x[lane+32]
}

// FINAL (session best, R14 = 371.5 us; baseline was 515.5): one block = one
// sample; 4 waves = 4 LSTM layers, elastic pipeline (16-deep f16 h-ring +
// progress counters, 8-step groups, no barrier in the recurrence).
//  - v_dot2_f32_f16 MACs (2 dims/instr, f32 accumulate); f16 weights = 60 regs
//  - h packed into f16 pairs (cvt + DPP quad-perm + or): 15 readlanes/step
//  - x read from ring as packed f16 pairs (4 uniform ds_read_b128/step)
//  - XOR-32 gate layout; single v_permlane32_swap per gate exchange
//  - s_setprio(1) around the 60-MAC burst, prio 0 for the serial activation
//    chain: the sibling block's wave fills the chain window (+6.3%, R14;
//    T5 mechanism, independent-block waves)
// Refuted alternatives (with evidence): SPB-ILP (R3/R9: compiler interleave
// loses to HW wave interleave), AGPR-operand VOP3P (R5: not encodable),
// MFMA-batched recurrence (R11/R12: 16x trans-pipe concentration on 32 CUs,
// k1 alone 403 us), software-pipelined x-side (R15: 410 us - textual
// reordering broke the compiler's lgkmcnt placement and the prio split).
__global__ __launch_bounds__(256) __attribute__((amdgpu_waves_per_eu(2, 2)))
void rnn_fused(
    const int*   __restrict__ xin,  const float* __restrict__ wxin,
    const float* __restrict__ embed,
    const float* __restrict__ Wih,  const float* __restrict__ Whh,
    const float* __restrict__ bih,  const float* __restrict__ bhh,
    const float* __restrict__ W1,   const float* __restrict__ b1,
    const float* __restrict__ W2,   const float* __restrict__ b2,
    const float* __restrict__ fcW,  const float* __restrict__ fcb,
    float* __restrict__ out)
{
    __shared__ alignas(16) float hstore[TT * HH];              // layer-3 h trace (f32)
    __shared__ alignas(16) unsigned int seqring16[2][16][16];  // pooled-embed, f16 pairs
    __shared__ alignas(16) int   ringx[4][16][KK];             // x stream (wave-0 private)
    __shared__ alignas(16) float ringw[4][16][KK];
    __shared__ alignas(16) unsigned int hring16[3][16][16];    // layer->layer h, f16 pairs
    __shared__ alignas(16) float re_s[5 * HH];                 // relu(embed)
    __shared__ alignas(16) float energy_s[TT];
    __shared__ float red_s[16];
    __shared__ float part_s[8][HH];
    __shared__ float pooled_s[HH];
    __shared__ float logits_s[3];
    __shared__ int   sync_s[8];                                // [0..3]=prog, [4..7]=cons

    const int tid  = threadIdx.x;
    const int wv   = tid >> 6;
    const int lane = tid & 63;
    const int b    = blockIdx.x;
    volatile int* vs = sync_s;

    // ---- preamble ----
    if (tid < 8) sync_s[tid] = 0;
    if (tid < 5 * HH) re_s[tid] = fmaxf(embed[tid], 0.0f);

    int4 hx = {0,0,0,0}; float4 hw = {0,0,0,0};          // held x/w (wave0, lanes<32)
    if (wv == 0 && lane < 32) {
        const int r = lane >> 1, hf = lane & 1;
        #pragma unroll
        for (int cc = 0; cc < 2; ++cc) {                 // chunks 0,1 -> LDS
            long off = ((long)(16 * cc + r) * BB + b) * KK + hf * 4;
            *(int4*)(&ringx[cc][r][hf * 4])   = *(const int4*)(xin  + off);
            *(float4*)(&ringw[cc][r][hf * 4]) = *(const float4*)(wxin + off);
        }
        long off2 = ((long)(32 + r) * BB + b) * KK + hf * 4;  // chunk 2 -> regs
        hx = *(const int4*)(xin  + off2);
        hw = *(const float4*)(wxin + off2);
    }

    // ---- per-lane LSTM weights, XOR-32 gate layout, packed f16 pairs ----
    // half0 (lanes 0..31):  rowA = i-row q,    rowB = g-row q+60
    // half1 (lanes 32..63): rowA = f-row q+30, rowB = o-row q+90
    const int half = lane >> 5;
    const int q31  = lane & 31;
    const int qq   = (q31 < HH) ? q31 : (HH - 1);        // clamp dead lanes
    const int rA   = qq + half * HH;                     // 0..59
    const int rB   = rA + 60;                            // 60..119
    half2v wihA_h[15], wihB_h[15], whhA_h[15], whhB_h[15];
    {
        const float* WihL = Wih + wv * GG * HH;
        const float* WhhL = Whh + wv * GG * HH;
        #pragma unroll
        for (int kk = 0; kk < 15; ++kk) {
            float2 a0 = *(const float2*)(WihL + rA * HH + 2 * kk);
            float2 a1 = *(const float2*)(WihL + rB * HH + 2 * kk);
            float2 a2 = *(const float2*)(WhhL + rA * HH + 2 * kk);
            float2 a3 = *(const float2*)(WhhL + rB * HH + 2 * kk);
            wihA_h[kk][0] = (_Float16)a0.x; wihA_h[kk][1] = (_Float16)a0.y;
            wihB_h[kk][0] = (_Float16)a1.x; wihB_h[kk][1] = (_Float16)a1.y;
            whhA_h[kk][0] = (_Float16)a2.x; whhA_h[kk][1] = (_Float16)a2.y;
            whhB_h[kk][0] = (_Float16)a3.x; whhB_h[kk][1] = (_Float16)a3.y;
        }
    }
    const float biasA = bih[wv * GG + rA] + bhh[wv * GG + rA];
    const float biasB = bih[wv * GG + rB] + bhh[wv * GG + rB];
    const float mBneg = (lane < 32) ? -2.0f : -1.0f;     // half0: tanh via 2*sig(2x)-1
    const float aB    = (lane < 32) ?  2.0f :  1.0f;
    const float dB    = (lane < 32) ? -1.0f :  0.0f;

    __syncthreads();   // preamble visible (ringx/re_s/sync init)

    float c_val = 0.0f;
    unsigned int hpk = 0;   // own h as packed f16 pair: even lane 2k holds (h2k, h2k+1)

    auto do_step = [&](int t) {
        // x operand: packed f16 pairs from ring, uniform-address b128 reads
        const unsigned int* xsrc = (wv == 0) ? &seqring16[(t >> 4) & 1][t & 15][0]
                                             : &hring16[wv - 1][t & 15][0];
        uint4 q0 = ((const uint4*)xsrc)[0];
        uint4 q1 = ((const uint4*)xsrc)[1];
        uint4 q2 = ((const uint4*)xsrc)[2];
        uint4 q3 = ((const uint4*)xsrc)[3];
        const unsigned int xu[16] = {q0.x,q0.y,q0.z,q0.w, q1.x,q1.y,q1.z,q1.w,
                                     q2.x,q2.y,q2.z,q2.w, q3.x,q3.y,q3.z,q3.w};
        // ---- MAC burst: high ILP, run at elevated priority ----
        __builtin_amdgcn_s_setprio(1);
        // h-side (chain-critical): 15 readlanes of packed pairs (even lanes)
        float ahA = 0.f, ahB = 0.f, ahA2 = 0.f, ahB2 = 0.f;
        #pragma unroll
        for (int k = 0; k < 8; ++k) {
            const half2v hp = as_h2(rdlane_u(hpk, 2 * k));
            ahA = __builtin_amdgcn_fdot2(whhA_h[k], hp, ahA, false);
            ahB = __builtin_amdgcn_fdot2(whhB_h[k], hp, ahB, false);
        }
        #pragma unroll
        for (int k = 8; k < 15; ++k) {
            const half2v hp = as_h2(rdlane_u(hpk, 2 * k));
            ahA2 = __builtin_amdgcn_fdot2(whhA_h[k], hp, ahA2, false);
            ahB2 = __builtin_amdgcn_fdot2(whhB_h[k], hp, ahB2, false);
        }
        // x-side: independent of h, fills h-chain stalls
        float axA = 0.f, axB = 0.f;
        #pragma unroll
        for (int k = 0; k < 15; ++k) {
            const half2v xp = as_h2(xu[k]);
            axA = __builtin_amdgcn_fdot2(wihA_h[k], xp, axA, false);
            axB = __builtin_amdgcn_fdot2(wihB_h[k], xp, axB, false);
        }
        // ---- serial activation chain: low ILP, drop priority so the
        // sibling block's wave gets the issue slots ----
        __builtin_amdgcn_s_setprio(0);
        const float gA = (axA + ahA) + (ahA2 + biasA);   // i | f
        const float gB = (axB + ahB) + (ahB2 + biasB);   // g | o
        const float actA = rcp_f(1.0f + __expf(-gA));    // sigmoid (both halves)
        const float sB   = rcp_f(1.0f + __expf(gB * mBneg));
        const float actB = fmaf(aB, sB, dB);             // tanh | sigmoid
        const float fI = swap32_hi(actA);                // f from lane+32
        const float oI = swap32_hi(actB);                // o from lane+32
        c_val = fmaf(fI, c_val, actA * actB);            // valid on lanes 0..29
        const float tC = fmaf(2.0f, rcp_f(1.0f + __expf(-2.0f * c_val)), -1.0f);
        const float hv = oI * tC;
        // pack f16 pair: own (lo) | quad-perm partner (hi) -- valid on even lanes
        union { _Float16 f[2]; unsigned int u; } cv; cv.u = 0;
        cv.f[0] = (_Float16)hv;
        const unsigned int hu  = cv.u;
        const unsigned int hup = (unsigned int)__builtin_amdgcn_mov_dpp(
                                     (int)hu, 0xB1, 0xF, 0xF, true); // quad_perm [1,0,3,2]
        hpk = hu | (hup << 16);
        if (lane < HH) {
            if (wv == NLAYER - 1) hstore[t * HH + lane] = hv;          // f32 trace
            else if (!(lane & 1)) hring16[wv][t & 15][lane >> 1] = hpk; // f16 pairs
        }
    };

    // ---- elastic pipelined recurrence: 64 groups of 8 steps ----
    for (int T0 = 0; T0 < TT; T0 += 8) {
        if (wv == 0) {
            if ((T0 & 15) == 0) {                        // chunk boundary (private)
                const int c = T0 >> 4;
                if (lane < 32) {
                    const int r = lane >> 1, hf = lane & 1;
                    if (c <= 29) {                       // commit chunk c+2
                        const int sl = (c + 2) & 3;
                        *(int4*)(&ringx[sl][r][hf * 4])   = hx;
                        *(float4*)(&ringw[sl][r][hf * 4]) = hw;
                    }
                    if (c <= 28) {                       // load chunk c+3
                        long off = ((long)(16 * (c + 3) + r) * BB + b) * KK + hf * 4;
                        hx = *(const int4*)(xin  + off);
                        hw = *(const float4*)(wxin + off);
                    }
                }
                const int sl = c & 3, par = c & 1;       // gather pooled chunk c
                #pragma unroll
                for (int rr = 0; rr < 8; ++rr) {
                    const int o = lane + rr * 64;
                    if (o < 480) {
                        const int tr = o / HH, j = o - tr * HH;
                        int4   xa = *(const int4*)(&ringx[sl][tr][0]);
                        int4   xb = *(const int4*)(&ringx[sl][tr][4]);
                        float4 wa = *(const float4*)(&ringw[sl][tr][0]);
                        float4 wb = *(const float4*)(&ringw[sl][tr][4]);
                        float acc = re_s[xa.x * HH + j] * wa.x;
                        acc = fmaf(re_s[xa.y * HH + j], wa.y, acc);
                        acc = fmaf(re_s[xa.z * HH + j], wa.z, acc);
                        acc = fmaf(re_s[xa.w * HH + j], wa.w, acc);
                        acc = fmaf(re_s[xb.x * HH + j], wb.x, acc);
                        acc = fmaf(re_s[xb.y * HH + j], wb.y, acc);
                        acc = fmaf(re_s[xb.z * HH + j], wb.z, acc);
                        acc = fmaf(re_s[xb.w * HH + j], wb.w, acc);
                        // store pooled value as f16 (u16 element j of the pair row)
                        ((_Float16*)&seqring16[par][tr][0])[j] = (_Float16)(acc * 0.125f);
                    }
                }
                __threadfence_block();                   // gather visible to own reads
            }
        } else {
            while (vs[wv - 1] < T0 + 8) __builtin_amdgcn_s_sleep(1);   // x ready
        }
        if (wv < NLAYER - 1) {
            while (vs[4 + wv + 1] < T0 - 8) __builtin_amdgcn_s_sleep(1); // ring free
        }
        __threadfence_block();                           // order spins vs ring reads
        #pragma unroll 1
        for (int tt = 0; tt < 8; ++tt)                   // NOT unrolled: ~1KB body
            do_step(T0 + tt);
        __threadfence_block();                           // drain h writes
        if (lane == 0) {
            if (wv < NLAYER - 1) vs[wv]     = T0 + 8;    // producer progress
            if (wv > 0)          vs[4 + wv] = T0 + 8;    // consumer progress
        }
    }

    __syncthreads();   // hstore complete

    // ---- attention, t-per-lane: e_t = relu(h_t @ W1 + b1) @ W2 + b2 ----
    {
        // launder pointers so these loop-invariant loads CANNOT be hoisted
        // above the recurrence
        const float* W1p = W1;
        const float* b1p = b1;
        const float* W2p = W2;
        asm volatile("" : "+v"(W1p), "+v"(b1p), "+v"(W2p));

        float w1cx[15], w1cy[15];                        // W1 column `lane`
        #pragma unroll
        for (int k = 0; k < 15; ++k) {
            w1cx[k] = W1p[(2 * k) * 64 + lane];
            w1cy[k] = W1p[(2 * k + 1) * 64 + lane];
        }
        const float b1v = b1p[lane];
        const float w2v = W2p[lane];
        const float b2v = b2[0];
        #pragma unroll
        for (int pass = 0; pass < 2; ++pass) {
            const int t = wv * 128 + pass * 64 + lane;   // each lane owns one t
            float2 h2[15];
            #pragma unroll
            for (int k = 0; k < 15; ++k)
                h2[k] = *(const float2*)(hstore + t * HH + 2 * k);
            float e = b2v;
            for (int u = 0; u < 64; ++u) {               // W1 broadcast via readlane
                float2 acc = {0.f, 0.f};
                #pragma unroll
                for (int k = 0; k < 15; ++k) {
                    float2 wp;
                    wp.x = rdlane_f(w1cx[k], u);
                    wp.y = rdlane_f(w1cy[k], u);
                    acc = pk_fma_s(h2[k], wp, acc);
                }
                const float su = acc.x + acc.y + rdlane_f(b1v, u);
                e = fmaf(fmaxf(su, 0.0f), rdlane_f(w2v, u), e);
            }
            energy_s[t] = e;
        }
    }
    __syncthreads();

    // ---- softmax over T ----
    float mx = -3.0e38f;
    for (int i = tid; i < TT; i += 256) mx = fmaxf(mx, energy_s[i]);
    #pragma unroll
    for (int m = 1; m < 64; m <<= 1) mx = fmaxf(mx, __shfl_xor(mx, m, 64));
    if (lane == 0) red_s[wv] = mx;
    __syncthreads();
    mx = fmaxf(fmaxf(red_s[0], red_s[1]), fmaxf(red_s[2], red_s[3]));
    float ssum = 0.0f;
    for (int i = tid; i < TT; i += 256) {
        float ev = __expf(energy_s[i] - mx);
        energy_s[i] = ev;
        ssum += ev;
    }
    #pragma unroll
    for (int m = 1; m < 64; m <<= 1) ssum += __shfl_xor(ssum, m, 64);
    if (lane == 0) red_s[8 + wv] = ssum;
    __syncthreads();
    const float invS = rcp_f(red_s[8] + red_s[9] + red_s[10] + red_s[11]);

    // ---- pooled_j = sum_t softmax_t * h[t][j] ----
    {
        const int g = tid >> 5, jj = tid & 31;
        if (jj < HH) {
            float part = 0.0f;
            for (int t = g; t < TT; t += 8)
                part = fmaf(energy_s[t] * invS, hstore[t * HH + jj], part);
            part_s[g][jj] = part;
        }
    }
    __syncthreads();
    if (tid < HH) {
        float pv = 0.0f;
        #pragma unroll
        for (int q = 0; q < 8; ++q) pv += part_s[q][tid];
        pooled_s[tid] = pv;
    }
    __syncthreads();

    // ---- FC (30->3) + softmax ----
    if (tid < 3) {
        float acc = fcb[tid];
        #pragma unroll
        for (int k = 0; k < HH; ++k) acc = fmaf(pooled_s[k], fcW[k * 3 + tid], acc);
        logits_s[tid] = acc;
    }
    __syncthreads();
    if (tid == 0) {
        float l0 = logits_s[0], l1 = logits_s[1], l2 = logits_s[2];
        float m3 = fmaxf(l0, fmaxf(l1, l2));
        float e0 = __expf(l0 - m3), e1 = __expf(l1 - m3), e2 = __expf(l2 - m3);
        float inv = rcp_f(e0 + e1 + e2);
        out[b * 3 + 0] = e0 * inv; out[b * 3 + 1] = e1 * inv; out[b * 3 + 2] = e2 * inv;
    }
}

extern "C" void kernel_launch(void* const* d_in, const int* in_sizes, int n_in,
                              void* d_out, int out_size, void* d_ws, size_t ws_size,
                              hipStream_t stream)
{
    (void)in_sizes; (void)n_in; (void)d_ws; (void)ws_size; (void)out_size;
    rnn_fused<<<BB, 256, 0, stream>>>(
        (const int*)  d_in[0],  (const float*)d_in[1],  (const float*)d_in[2],
        (const float*)d_in[3],  (const float*)d_in[4],  (const float*)d_in[5],
        (const float*)d_in[6],  (const float*)d_in[7],  (const float*)d_in[8],
        (const float*)d_in[9],  (const float*)d_in[10], (const float*)d_in[11],
        (const float*)d_in[12], (float*)d_out);
}